// Round 10
// baseline (248.024 us; speedup 1.0000x reference)
//
#include <hip/hip_runtime.h>

// B=8, T=2048, C=1024, H=64.  Reference: softmax over QUERY axis (dim=1),
// no 1/sqrt(d) scale.  out[t,h] = sum_{s<=t} exp(q_t.k_s)/D_s * v[s,h],
// D_s = sum_{t>=s} exp(q_t.k_s).
// Split-bf16 (hi+lo, 3-term) MFMA for qkv GEMM and QK dots (~fp32 accuracy);
// plain bf16 for V and P in PV (~0.4% rel).
// Round-10: qkv is BARRIER-FREE (no LDS; A-frags direct global->VGPR with
// in-register hi/lo split; waves free-run -> no vmcnt(0) barrier drain, the
// suspected r6/r9 62us invariant).  out drops qt LDS (q-frags in regs,
// 36KB LDS -> 4 blk/CU) and chunks at 4; stats chunks at 4.

typedef __attribute__((ext_vector_type(8))) short bf16x8;
typedef __attribute__((ext_vector_type(4))) float f32x4;
typedef unsigned short u16;

#define MFMA(a, b, c) __builtin_amdgcn_mfma_f32_16x16x32_bf16((a), (b), (c), 0, 0, 0)

__device__ __forceinline__ u16 f2bf(float x) {           // RNE fp32 -> bf16
    unsigned u = __float_as_uint(x);
    u += 0x7fff + ((u >> 16) & 1);
    return (u16)(u >> 16);
}
__device__ __forceinline__ float bf2f(u16 h) {
    return __uint_as_float(((unsigned)h) << 16);
}

// ws byte offsets
#define WH_OFF 0u
#define WL_OFF (WH_OFF + 192u*1024u*2u)
#define QH_OFF (WL_OFF + 192u*1024u*2u)
#define QL_OFF (QH_OFF + 8u*2048u*64u*2u)
#define KH_OFF (QL_OFF + 8u*2048u*64u*2u)
#define KL_OFF (KH_OFF + 8u*2048u*64u*2u)
#define VT_OFF (KL_OFF + 8u*2048u*64u*2u)
#define DD_OFF (VT_OFF + 8u*2048u*64u*2u)   // fp32 [B][T]

// ---------------------------------------------------------------------------
// W pre-split: rows 0..63 = Wq, 64..127 = Wk, 128..191 = Wv
// ---------------------------------------------------------------------------
__global__ __launch_bounds__(256) void wsplit_kernel(
    const float* __restrict__ Wk, const float* __restrict__ Wq,
    const float* __restrict__ Wv, u16* __restrict__ WH, u16* __restrict__ WL)
{
    const int n = blockIdx.x;
    const float* src = (n < 64) ? (Wq + (long)n * 1024)
                     : (n < 128) ? (Wk + (long)(n - 64) * 1024)
                                 : (Wv + (long)(n - 128) * 1024);
    const float4 f = ((const float4*)src)[threadIdx.x];
    const float v[4] = {f.x, f.y, f.z, f.w};
    u16 hi[4], lo[4];
    #pragma unroll
    for (int j = 0; j < 4; ++j) {
        hi[j] = f2bf(v[j]);
        lo[j] = f2bf(v[j] - bf2f(hi[j]));
    }
    *(ushort4*)&WH[(long)n * 1024 + 4 * threadIdx.x] = make_ushort4(hi[0], hi[1], hi[2], hi[3]);
    *(ushort4*)&WL[(long)n * 1024 + 4 * threadIdx.x] = make_ushort4(lo[0], lo[1], lo[2], lo[3]);
}

// ---------------------------------------------------------------------------
// qkv: [16384x1024] @ [1024x192], BARRIER-FREE.  512 thr = 8 waves (2m x 4n);
// M-tile 32, grid 512.  Wave (mw, nw) owns rows mw*16..+15, cols nw*48..+47.
// A frags loaded direct global->VGPR (fp32) and hi/lo-split in registers;
// W frags direct global (bf16 pre-split).  No LDS, no __syncthreads.
// ---------------------------------------------------------------------------
__global__ __launch_bounds__(512, 4) void qkv_kernel(
    const float* __restrict__ idx, const u16* __restrict__ WH, const u16* __restrict__ WL,
    u16* __restrict__ QH, u16* __restrict__ QL,
    u16* __restrict__ KH, u16* __restrict__ KL, u16* __restrict__ VT)
{
    const int tid = threadIdx.x;
    const int w = tid >> 6, lr = tid & 15, quad = (tid >> 4) & 3;
    const int mw = w & 1, nw = w >> 1;
    const int r0 = blockIdx.x * 32;
    const int b = r0 >> 11, t0 = r0 & 2047;
    const int nb = nw * 48;
    const float* arow = &idx[(long)(r0 + mw * 16 + lr) * 1024 + quad * 8];

    f32x4 acc[3] = {};

    for (int it = 0; it < 16; ++it) {
        const int c0 = it * 64;
        // A frags: 16 rows x 64 cols fp32, direct load + in-register split
        bf16x8 ah[2], al[2];
        #pragma unroll
        for (int kc = 0; kc < 2; ++kc) {
            const float4 f0 = *(const float4*)(arow + c0 + kc * 32);
            const float4 f1 = *(const float4*)(arow + c0 + kc * 32 + 4);
            const float vs[8] = {f0.x, f0.y, f0.z, f0.w, f1.x, f1.y, f1.z, f1.w};
            #pragma unroll
            for (int j = 0; j < 8; ++j) {
                const u16 h = f2bf(vs[j]);
                ah[kc][j] = (short)h;
                al[kc][j] = (short)f2bf(vs[j] - bf2f(h));
            }
        }
        #pragma unroll
        for (int nf = 0; nf < 3; ++nf) {
            const long wr = (long)(nb + nf * 16 + lr) * 1024 + c0 + quad * 8;
            const bf16x8 bh0 = *(const bf16x8*)&WH[wr];
            const bf16x8 bh1 = *(const bf16x8*)&WH[wr + 32];
            const bf16x8 bl0 = *(const bf16x8*)&WL[wr];
            const bf16x8 bl1 = *(const bf16x8*)&WL[wr + 32];
            f32x4 c = acc[nf];
            c = MFMA(ah[0], bh0, c);
            c = MFMA(al[0], bh0, c);
            c = MFMA(ah[0], bl0, c);
            c = MFMA(ah[1], bh1, c);
            c = MFMA(al[1], bh1, c);
            c = MFMA(ah[1], bl1, c);
            acc[nf] = c;
        }
    }

    // epilogue: C layout col = lane&15 (n), row = quad*4 + reg (m)
    const int tb = t0 + mw * 16 + quad * 4;
    #pragma unroll
    for (int nf = 0; nf < 3; ++nf) {
        const int n = nb + nf * 16 + lr;
        const f32x4 a = acc[nf];
        if (n < 128) {
            u16* Hd = (n < 64) ? QH : KH;
            u16* Ld = (n < 64) ? QL : KL;
            const int h = n & 63;
            #pragma unroll
            for (int r = 0; r < 4; ++r) {
                const float v = a[r];
                const u16 hi = f2bf(v);
                const u16 lo = f2bf(v - bf2f(hi));
                const long o = (long)(b * 2048 + tb + r) * 64 + h;
                Hd[o] = hi; Ld[o] = lo;
            }
        } else {
            *(ushort4*)&VT[(long)(b * 64 + n - 128) * 2048 + tb] =
                make_ushort4(f2bf(a[0]), f2bf(a[1]), f2bf(a[2]), f2bf(a[3]));
        }
    }
}

// ---------------------------------------------------------------------------
// stats: D_s = sum_{t>=s} exp(q_t.k_s).  LDS-staged kt/qt (r4 structure),
// chunk 4 -> grid (144, B) for occupancy.  atomicAdd partials.
// ---------------------------------------------------------------------------
__global__ __launch_bounds__(256, 4) void stats_kernel(
    const u16* __restrict__ QH, const u16* __restrict__ QL,
    const u16* __restrict__ KH, const u16* __restrict__ KL,
    float* __restrict__ D)
{
    __shared__ u16 kt[64 * 136];
    __shared__ u16 qt[64 * 136];
    __shared__ float red[4][64];
    const int tid = threadIdx.x;
    const int w = tid >> 6, lr = tid & 15, quad = (tid >> 4) & 3;
    const int b = blockIdx.y;
    int x = blockIdx.x, i = 0;
    for (;;) { const int nc = (35 - i) >> 2; if (x < nc) break; x -= nc; ++i; }
    const int c = x;
    const int s0 = i * 64;

    #pragma unroll
    for (int it = 0; it < 2; ++it) {
        const int e = it * 256 + tid;
        const int s = e >> 3, c8 = e & 7;
        const long g = (long)(b * 2048 + s0 + s) * 64 + 8 * c8;
        *(float4*)&kt[s * 136 + 8 * c8]      = *(const float4*)&KH[g];
        *(float4*)&kt[s * 136 + 64 + 8 * c8] = *(const float4*)&KL[g];
    }

    float dsum[4] = {0.f, 0.f, 0.f, 0.f};
    const int ar = (w * 16 + lr) * 136;
    const int jt0 = i + 4 * c, jt1 = min(i + 4 * c + 4, 32);
    for (int jt = jt0; jt < jt1; ++jt) {
        __syncthreads();
        #pragma unroll
        for (int it = 0; it < 2; ++it) {
            const int e = it * 256 + tid;
            const int t = e >> 3, c8 = e & 7;
            const long g = (long)(b * 2048 + jt * 64 + t) * 64 + 8 * c8;
            *(float4*)&qt[t * 136 + 8 * c8]      = *(const float4*)&QH[g];
            *(float4*)&qt[t * 136 + 64 + 8 * c8] = *(const float4*)&QL[g];
        }
        __syncthreads();

        const bf16x8 ah0 = *(const bf16x8*)&qt[ar + quad * 8];
        const bf16x8 al0 = *(const bf16x8*)&qt[ar + 64 + quad * 8];
        const bf16x8 ah1 = *(const bf16x8*)&qt[ar + 32 + quad * 8];
        const bf16x8 al1 = *(const bf16x8*)&qt[ar + 96 + quad * 8];
        #pragma unroll
        for (int nf = 0; nf < 4; ++nf) {
            const int br = (nf * 16 + lr) * 136;
            f32x4 cc = {};
            const bf16x8 bh0 = *(const bf16x8*)&kt[br + quad * 8];
            const bf16x8 bl0 = *(const bf16x8*)&kt[br + 64 + quad * 8];
            cc = MFMA(ah0, bh0, cc); cc = MFMA(ah0, bl0, cc); cc = MFMA(al0, bh0, cc);
            const bf16x8 bh1 = *(const bf16x8*)&kt[br + 32 + quad * 8];
            const bf16x8 bl1 = *(const bf16x8*)&kt[br + 96 + quad * 8];
            cc = MFMA(ah1, bh1, cc); cc = MFMA(ah1, bl1, cc); cc = MFMA(al1, bh1, cc);

            if (jt > i) {
                dsum[nf] += __expf(cc[0]) + __expf(cc[1]) + __expf(cc[2]) + __expf(cc[3]);
            } else {   // diagonal tile: include t >= s
                const int sl = nf * 16 + lr;
                #pragma unroll
                for (int r = 0; r < 4; ++r) {
                    const int tl = w * 16 + quad * 4 + r;
                    if (tl >= sl) dsum[nf] += __expf(cc[r]);
                }
            }
        }
    }

    #pragma unroll
    for (int nf = 0; nf < 4; ++nf) {
        dsum[nf] += __shfl_xor(dsum[nf], 16);
        dsum[nf] += __shfl_xor(dsum[nf], 32);
    }
    if (quad == 0) {
        #pragma unroll
        for (int nf = 0; nf < 4; ++nf) red[w][nf * 16 + lr] = dsum[nf];
    }
    __syncthreads();
    if (tid < 64)
        atomicAdd(&D[b * 2048 + s0 + tid],
                  red[0][tid] + red[1][tid] + red[2][tid] + red[3][tid]);
}

// ---------------------------------------------------------------------------
// out: per t-tile, loop s-tiles <= t.  Q A-frags in REGISTERS (no qt LDS);
// kt/vt LDS-staged; wa LDS for P transpose (own-wave strip).  LDS ~36KB ->
// 4 blocks/CU.  Chunk 4 -> grid (144, B).
// ---------------------------------------------------------------------------
__global__ __launch_bounds__(256, 4) void out_kernel(
    const u16* __restrict__ QH, const u16* __restrict__ QL,
    const u16* __restrict__ KH, const u16* __restrict__ KL,
    const u16* __restrict__ VT, const float* __restrict__ D,
    float* __restrict__ out)
{
    __shared__ u16 kt[64 * 136];
    __shared__ u16 vt[64 * 72];
    __shared__ u16 wa[64 * 72];
    __shared__ float rdt[64];
    const int tid = threadIdx.x;
    const int w = tid >> 6, lr = tid & 15, quad = (tid >> 4) & 3;
    const int b = blockIdx.y;
    int x = blockIdx.x, i = 0;
    for (;;) { const int nc = (i + 4) >> 2; if (x < nc) break; x -= nc; ++i; }
    const int t0 = i * 64;
    const int js0 = 4 * x, js1 = min(4 * x + 4, i + 1);

    // q A-frags direct global -> registers (rows t0 + w*16 + lr)
    const long qr = (long)(b * 2048 + t0 + w * 16 + lr) * 64 + quad * 8;
    const bf16x8 qh0 = *(const bf16x8*)&QH[qr];
    const bf16x8 qh1 = *(const bf16x8*)&QH[qr + 32];
    const bf16x8 ql0 = *(const bf16x8*)&QL[qr];
    const bf16x8 ql1 = *(const bf16x8*)&QL[qr + 32];

    f32x4 oacc[4] = {};
    for (int js = js0; js < js1; ++js) {
        const int s0 = js * 64;
        __syncthreads();
        #pragma unroll
        for (int it = 0; it < 2; ++it) {
            const int e = it * 256 + tid;
            const int s = e >> 3, c8 = e & 7;
            const long g = (long)(b * 2048 + s0 + s) * 64 + 8 * c8;
            *(float4*)&kt[s * 136 + 8 * c8]      = *(const float4*)&KH[g];
            *(float4*)&kt[s * 136 + 64 + 8 * c8] = *(const float4*)&KL[g];
        }
        #pragma unroll
        for (int it = 0; it < 2; ++it) {
            const int e = it * 256 + tid;
            const int h = e >> 3, c8 = e & 7;
            *(float4*)&vt[h * 72 + 8 * c8] =
                *(const float4*)&VT[(long)(b * 64 + h) * 2048 + s0 + 8 * c8];
        }
        if (tid < 64) rdt[tid] = 1.0f / D[b * 2048 + s0 + tid];
        __syncthreads();

        const bool diag = (js == i);
        #pragma unroll
        for (int nf = 0; nf < 4; ++nf) {
            const int br = (nf * 16 + lr) * 136;
            f32x4 cc = {};
            const bf16x8 bh0 = *(const bf16x8*)&kt[br + quad * 8];
            const bf16x8 bl0 = *(const bf16x8*)&kt[br + 64 + quad * 8];
            cc = MFMA(qh0, bh0, cc); cc = MFMA(qh0, bl0, cc); cc = MFMA(ql0, bh0, cc);
            const bf16x8 bh1 = *(const bf16x8*)&kt[br + 32 + quad * 8];
            const bf16x8 bl1 = *(const bf16x8*)&kt[br + 96 + quad * 8];
            cc = MFMA(qh1, bh1, cc); cc = MFMA(qh1, bl1, cc); cc = MFMA(ql1, bh1, cc);

            const int sl = nf * 16 + lr;
            const float rv = rdt[sl];
            #pragma unroll
            for (int r = 0; r < 4; ++r) {
                const int tl = w * 16 + quad * 4 + r;
                float wgt = __expf(cc[r]) * rv;
                if (diag && tl < sl) wgt = 0.f;
                wa[tl * 72 + sl] = f2bf(wgt);     // own-wave strip only
            }
        }
        // PV: A = wa strip (own rows), B = vt [h][s]
        #pragma unroll
        for (int kk = 0; kk < 2; ++kk) {
            const bf16x8 av = *(const bf16x8*)&wa[(w * 16 + lr) * 72 + kk * 32 + quad * 8];
            #pragma unroll
            for (int nf = 0; nf < 4; ++nf) {
                const bf16x8 bv = *(const bf16x8*)&vt[(nf * 16 + lr) * 72 + kk * 32 + quad * 8];
                oacc[nf] = MFMA(av, bv, oacc[nf]);
            }
        }
    }

    const bool single = (i < 4);
    #pragma unroll
    for (int nf = 0; nf < 4; ++nf) {
        const int h = nf * 16 + lr;
        #pragma unroll
        for (int r = 0; r < 4; ++r) {
            const int t = t0 + w * 16 + quad * 4 + r;
            const long o = (long)(b * 2048 + t) * 64 + h;
            if (single) out[o] = oacc[nf][r];
            else        atomicAdd(&out[o], oacc[nf][r]);
        }
    }
}

extern "C" void kernel_launch(void* const* d_in, const int* in_sizes, int n_in,
                              void* d_out, int out_size, void* d_ws, size_t ws_size,
                              hipStream_t stream)
{
    const float* idx = (const float*)d_in[0];
    const float* Wk  = (const float*)d_in[1];
    const float* Wq  = (const float*)d_in[2];
    const float* Wv  = (const float*)d_in[3];
    char* ws = (char*)d_ws;
    float* out = (float*)d_out;

    u16* WH = (u16*)(ws + WH_OFF); u16* WL = (u16*)(ws + WL_OFF);
    u16* QH = (u16*)(ws + QH_OFF); u16* QL = (u16*)(ws + QL_OFF);
    u16* KH = (u16*)(ws + KH_OFF); u16* KL = (u16*)(ws + KL_OFF);
    u16* VT = (u16*)(ws + VT_OFF);
    float* Dp = (float*)(ws + DD_OFF);

    hipMemsetAsync(out, 0, (size_t)8 * 2048 * 64 * sizeof(float), stream);
    hipMemsetAsync(Dp, 0, (size_t)8 * 2048 * sizeof(float), stream);

    wsplit_kernel<<<192, 256, 0, stream>>>(Wk, Wq, Wv, WH, WL);
    qkv_kernel<<<512, 512, 0, stream>>>(idx, WH, WL, QH, QL, KH, KL, VT);
    stats_kernel<<<dim3(144, 8), 256, 0, stream>>>(QH, QL, KH, KL, Dp);
    out_kernel<<<dim3(144, 8), 256, 0, stream>>>(QH, QL, KH, KL, VT, Dp, out);
}

// Round 11
// 169.256 us; speedup vs baseline: 1.4654x; 1.4654x over previous
//
#include <hip/hip_runtime.h>

// B=8, T=2048, C=1024, H=64.  Reference: softmax over QUERY axis (dim=1),
// no 1/sqrt(d) scale.  out[t,h] = sum_{s<=t} exp(q_t.k_s)/D_s * v[s,h],
// D_s = sum_{t>=s} exp(q_t.k_s).
// Split-bf16 (hi+lo, 3-term) MFMA for qkv GEMM and QK dots (~fp32 accuracy);
// plain bf16 for V and P in PV (~0.4% rel).
// Round-11: W stored in MFMA-FRAGMENT-COALESCED layout
//   FW[((nblk*32 + kc)*64 + lane)*8]  (lane = quad*16+lr, 16B/lane)
// so each wave B-frag load is one contiguous 1KB burst.  r9/r10 W loads had
// 4KB lane stride -> 64 cache lines per instruction (~64cyc TA serialization
// each) — the measured ~9.3k cyc/iter invariant.  qkv otherwise = r9
// (measured-best); stats/out = r9 verbatim.

typedef __attribute__((ext_vector_type(8))) short bf16x8;
typedef __attribute__((ext_vector_type(4))) float f32x4;
typedef unsigned short u16;

#define MFMA(a, b, c) __builtin_amdgcn_mfma_f32_16x16x32_bf16((a), (b), (c), 0, 0, 0)

__device__ __forceinline__ u16 f2bf(float x) {           // RNE fp32 -> bf16
    unsigned u = __float_as_uint(x);
    u += 0x7fff + ((u >> 16) & 1);
    return (u16)(u >> 16);
}
__device__ __forceinline__ float bf2f(u16 h) {
    return __uint_as_float(((unsigned)h) << 16);
}

// ws byte offsets
#define WH_OFF 0u
#define WL_OFF (WH_OFF + 192u*1024u*2u)
#define QH_OFF (WL_OFF + 192u*1024u*2u)
#define QL_OFF (QH_OFF + 8u*2048u*64u*2u)
#define KH_OFF (QL_OFF + 8u*2048u*64u*2u)
#define KL_OFF (KH_OFF + 8u*2048u*64u*2u)
#define VT_OFF (KL_OFF + 8u*2048u*64u*2u)
#define DD_OFF (VT_OFF + 8u*2048u*64u*2u)   // fp32 [B][T]

// ---------------------------------------------------------------------------
// W pre-split into FRAGMENT-COALESCED layout.  Logical W rows: 0..63 = Wq,
// 64..127 = Wk, 128..191 = Wv.  Row n = (nblk = n>>4, lr = n&15).  Fragment
// (nblk, kc, quad): 8 bf16 from cols kc*32 + quad*8; stored at
// ((nblk*32+kc)*64 + quad*16 + lr) * 8.
// ---------------------------------------------------------------------------
__global__ __launch_bounds__(128) void wsplit_kernel(
    const float* __restrict__ Wk, const float* __restrict__ Wq,
    const float* __restrict__ Wv, u16* __restrict__ FWH, u16* __restrict__ FWL)
{
    const int n = blockIdx.x;                 // 0..191
    const int nblk = n >> 4, lr = n & 15;
    const float* src = (n < 64) ? (Wq + (long)n * 1024)
                     : (n < 128) ? (Wk + (long)(n - 64) * 1024)
                                 : (Wv + (long)(n - 128) * 1024);
    const int f = threadIdx.x;                // 0..127 fragment id
    const int kc = f >> 2, q = f & 3;
    const float4 f0 = *(const float4*)&src[kc * 32 + q * 8];
    const float4 f1 = *(const float4*)&src[kc * 32 + q * 8 + 4];
    const float vs[8] = {f0.x, f0.y, f0.z, f0.w, f1.x, f1.y, f1.z, f1.w};
    bf16x8 hv, lv;
    #pragma unroll
    for (int j = 0; j < 8; ++j) {
        const u16 h = f2bf(vs[j]);
        hv[j] = (short)h;
        lv[j] = (short)f2bf(vs[j] - bf2f(h));
    }
    const long o = ((long)(nblk * 32 + kc) * 64 + q * 16 + lr) * 8;
    *(bf16x8*)&FWH[o] = hv;
    *(bf16x8*)&FWL[o] = lv;
}

// ---------------------------------------------------------------------------
// qkv: [16384x1024] @ [1024x192].  M-tile 64, 512 thr = 8 waves (2m x 4n:
// wave w -> m0=(w&1)*32, nblk base=(w>>1)*3).  A-tile double-buffered LDS
// (fp32 -> hi/lo split); W frags from FRAGMENT-COALESCED global layout
// (1KB contiguous per load).  a_l rows: [hi 64 | lo 64 | pad 8] u16 = 272B.
// Grid 256.
// ---------------------------------------------------------------------------
__global__ __launch_bounds__(512, 2) void qkv_kernel(
    const float* __restrict__ idx, const u16* __restrict__ FWH, const u16* __restrict__ FWL,
    u16* __restrict__ QH, u16* __restrict__ QL,
    u16* __restrict__ KH, u16* __restrict__ KL, u16* __restrict__ VT)
{
    __shared__ u16 a_l[2][64 * 136];
    const int tid = threadIdx.x;
    const int w = tid >> 6, lr = tid & 15, quad = (tid >> 4) & 3;
    const int lane = tid & 63;
    const int r0 = blockIdx.x * 64;
    const int b = r0 >> 11, t0 = r0 & 2047;
    const int m0 = (w & 1) * 32;
    const int nbb = (w >> 1) * 3;              // nblk base for this wave
    const int sr = tid >> 3, sc = (tid & 7) * 8;   // staging: row, col-start
    const float* arow = &idx[(long)(r0 + sr) * 1024 + sc];

    f32x4 acc[2][3] = {};
    float4 pf0, pf1;

    // prologue: stage chunk 0
    pf0 = *(const float4*)(arow);
    pf1 = *(const float4*)(arow + 4);
    {
        const float vs[8] = {pf0.x, pf0.y, pf0.z, pf0.w, pf1.x, pf1.y, pf1.z, pf1.w};
        bf16x8 hv, lv;
        #pragma unroll
        for (int j = 0; j < 8; ++j) {
            const u16 h = f2bf(vs[j]);
            hv[j] = (short)h;
            lv[j] = (short)f2bf(vs[j] - bf2f(h));
        }
        *(bf16x8*)&a_l[0][sr * 136 + sc]      = hv;
        *(bf16x8*)&a_l[0][sr * 136 + 64 + sc] = lv;
    }
    __syncthreads();

    int p = 0;
    for (int it = 0; it < 16; ++it) {
        const int c0 = it * 64;
        if (it < 15) {   // register prefetch of next A chunk
            pf0 = *(const float4*)(arow + c0 + 64);
            pf1 = *(const float4*)(arow + c0 + 68);
        }

        // A frags from LDS
        bf16x8 AH[2][2], AL[2][2];
        #pragma unroll
        for (int mi = 0; mi < 2; ++mi) {
            const int ar = (m0 + mi * 16 + lr) * 136 + quad * 8;
            AH[mi][0] = *(const bf16x8*)&a_l[p][ar];
            AH[mi][1] = *(const bf16x8*)&a_l[p][ar + 32];
            AL[mi][0] = *(const bf16x8*)&a_l[p][ar + 64];
            AL[mi][1] = *(const bf16x8*)&a_l[p][ar + 96];
        }

        #pragma unroll
        for (int nf = 0; nf < 3; ++nf) {
            // fragment-coalesced W: kc pair (2*it, 2*it+1), lane-contiguous
            const long base = ((long)((nbb + nf) * 32 + 2 * it) * 64 + lane) * 8;
            const bf16x8 bh0 = *(const bf16x8*)&FWH[base];
            const bf16x8 bh1 = *(const bf16x8*)&FWH[base + 512];
            const bf16x8 bl0 = *(const bf16x8*)&FWL[base];
            const bf16x8 bl1 = *(const bf16x8*)&FWL[base + 512];
            #pragma unroll
            for (int mi = 0; mi < 2; ++mi) {
                f32x4 c = acc[mi][nf];
                c = MFMA(AH[mi][0], bh0, c);
                c = MFMA(AL[mi][0], bh0, c);
                c = MFMA(AH[mi][0], bl0, c);
                c = MFMA(AH[mi][1], bh1, c);
                c = MFMA(AL[mi][1], bh1, c);
                c = MFMA(AH[mi][1], bl1, c);
                acc[mi][nf] = c;
            }
        }

        if (it < 15) {
            const float vs[8] = {pf0.x, pf0.y, pf0.z, pf0.w, pf1.x, pf1.y, pf1.z, pf1.w};
            bf16x8 hv, lv;
            #pragma unroll
            for (int j = 0; j < 8; ++j) {
                const u16 h = f2bf(vs[j]);
                hv[j] = (short)h;
                lv[j] = (short)f2bf(vs[j] - bf2f(h));
            }
            *(bf16x8*)&a_l[p ^ 1][sr * 136 + sc]      = hv;
            *(bf16x8*)&a_l[p ^ 1][sr * 136 + 64 + sc] = lv;
            __syncthreads();
            p ^= 1;
        }
    }

    // epilogue: C layout col = lane&15 (n), row = quad*4 + reg (m)
    #pragma unroll
    for (int mi = 0; mi < 2; ++mi) {
        const int tb = t0 + m0 + mi * 16 + quad * 4;
        #pragma unroll
        for (int nf = 0; nf < 3; ++nf) {
            const int n = (nbb + nf) * 16 + lr;
            const f32x4 a = acc[mi][nf];
            if (n < 128) {
                u16* Hd = (n < 64) ? QH : KH;
                u16* Ld = (n < 64) ? QL : KL;
                const int h = n & 63;
                #pragma unroll
                for (int r = 0; r < 4; ++r) {
                    const float v = a[r];
                    const u16 hi = f2bf(v);
                    const u16 lo = f2bf(v - bf2f(hi));
                    const long o = (long)(b * 2048 + tb + r) * 64 + h;
                    Hd[o] = hi; Ld[o] = lo;
                }
            } else {
                *(ushort4*)&VT[(long)(b * 64 + n - 128) * 2048 + tb] =
                    make_ushort4(f2bf(a[0]), f2bf(a[1]), f2bf(a[2]), f2bf(a[3]));
            }
        }
    }
}

// ---------------------------------------------------------------------------
// stats (r9 verbatim): D_s = sum_{t>=s} exp(q_t.k_s).  LDS-staged kt/qt,
// 6-mfma split dots.  Grid (80, B): s-tile i, t-chunk c (<=8); atomicAdd.
// ---------------------------------------------------------------------------
__global__ __launch_bounds__(256) void stats_kernel(
    const u16* __restrict__ QH, const u16* __restrict__ QL,
    const u16* __restrict__ KH, const u16* __restrict__ KL,
    float* __restrict__ D)
{
    __shared__ u16 kt[64 * 136];
    __shared__ u16 qt[64 * 136];
    __shared__ float red[4][64];
    const int tid = threadIdx.x;
    const int w = tid >> 6, lr = tid & 15, quad = (tid >> 4) & 3;
    const int b = blockIdx.y;
    int x = blockIdx.x, i = 0;
    for (;;) { const int nc = (39 - i) >> 3; if (x < nc) break; x -= nc; ++i; }
    const int c = x;
    const int s0 = i * 64;

    #pragma unroll
    for (int it = 0; it < 2; ++it) {
        const int e = it * 256 + tid;
        const int s = e >> 3, c8 = e & 7;
        const long g = (long)(b * 2048 + s0 + s) * 64 + 8 * c8;
        *(float4*)&kt[s * 136 + 8 * c8]      = *(const float4*)&KH[g];
        *(float4*)&kt[s * 136 + 64 + 8 * c8] = *(const float4*)&KL[g];
    }

    float dsum[4] = {0.f, 0.f, 0.f, 0.f};
    const int ar = (w * 16 + lr) * 136;
    const int jt1 = min(i + 8 * c + 8, 32);
    for (int jt = i + 8 * c; jt < jt1; ++jt) {
        __syncthreads();
        #pragma unroll
        for (int it = 0; it < 2; ++it) {
            const int e = it * 256 + tid;
            const int t = e >> 3, c8 = e & 7;
            const long g = (long)(b * 2048 + jt * 64 + t) * 64 + 8 * c8;
            *(float4*)&qt[t * 136 + 8 * c8]      = *(const float4*)&QH[g];
            *(float4*)&qt[t * 136 + 64 + 8 * c8] = *(const float4*)&QL[g];
        }
        __syncthreads();

        const bf16x8 ah0 = *(const bf16x8*)&qt[ar + quad * 8];
        const bf16x8 al0 = *(const bf16x8*)&qt[ar + 64 + quad * 8];
        const bf16x8 ah1 = *(const bf16x8*)&qt[ar + 32 + quad * 8];
        const bf16x8 al1 = *(const bf16x8*)&qt[ar + 96 + quad * 8];
        #pragma unroll
        for (int nf = 0; nf < 4; ++nf) {
            const int br = (nf * 16 + lr) * 136;
            f32x4 cc = {};
            const bf16x8 bh0 = *(const bf16x8*)&kt[br + quad * 8];
            const bf16x8 bl0 = *(const bf16x8*)&kt[br + 64 + quad * 8];
            cc = MFMA(ah0, bh0, cc); cc = MFMA(ah0, bl0, cc); cc = MFMA(al0, bh0, cc);
            const bf16x8 bh1 = *(const bf16x8*)&kt[br + 32 + quad * 8];
            const bf16x8 bl1 = *(const bf16x8*)&kt[br + 96 + quad * 8];
            cc = MFMA(ah1, bh1, cc); cc = MFMA(ah1, bl1, cc); cc = MFMA(al1, bh1, cc);

            if (jt > i) {
                dsum[nf] += __expf(cc[0]) + __expf(cc[1]) + __expf(cc[2]) + __expf(cc[3]);
            } else {   // diagonal tile: include t >= s
                const int sl = nf * 16 + lr;
                #pragma unroll
                for (int r = 0; r < 4; ++r) {
                    const int tl = w * 16 + quad * 4 + r;
                    if (tl >= sl) dsum[nf] += __expf(cc[r]);
                }
            }
        }
    }

    #pragma unroll
    for (int nf = 0; nf < 4; ++nf) {
        dsum[nf] += __shfl_xor(dsum[nf], 16);
        dsum[nf] += __shfl_xor(dsum[nf], 32);
    }
    if (quad == 0) {
        #pragma unroll
        for (int nf = 0; nf < 4; ++nf) red[w][nf * 16 + lr] = dsum[nf];
    }
    __syncthreads();
    if (tid < 64)
        atomicAdd(&D[b * 2048 + s0 + tid],
                  red[0][tid] + red[1][tid] + red[2][tid] + red[3][tid]);
}

// ---------------------------------------------------------------------------
// out (r9 verbatim): per t-tile, loop s-tiles <= t.  LDS-staged qt/kt/vt,
// split dots -> w = exp * (1/D_s) masked -> bf16 LDS wa (A-layout, own-wave
// strip) -> PV mfma -> store / atomicAdd.  Grid (80, B).
// ---------------------------------------------------------------------------
__global__ __launch_bounds__(256) void out_kernel(
    const u16* __restrict__ QH, const u16* __restrict__ QL,
    const u16* __restrict__ KH, const u16* __restrict__ KL,
    const u16* __restrict__ VT, const float* __restrict__ D,
    float* __restrict__ out)
{
    __shared__ u16 qt[64 * 136];
    __shared__ u16 kt[64 * 136];
    __shared__ u16 vt[64 * 72];
    __shared__ u16 wa[64 * 72];
    __shared__ float rdt[64];
    const int tid = threadIdx.x;
    const int w = tid >> 6, lr = tid & 15, quad = (tid >> 4) & 3;
    const int b = blockIdx.y;
    int x = blockIdx.x, i = 0;
    for (;;) { const int nc = (i + 8) >> 3; if (x < nc) break; x -= nc; ++i; }
    const int c = x;
    const int t0 = i * 64;

    #pragma unroll
    for (int it = 0; it < 2; ++it) {   // stage Q tile once
        const int e = it * 256 + tid;
        const int t = e >> 3, c8 = e & 7;
        const long g = (long)(b * 2048 + t0 + t) * 64 + 8 * c8;
        *(float4*)&qt[t * 136 + 8 * c8]      = *(const float4*)&QH[g];
        *(float4*)&qt[t * 136 + 64 + 8 * c8] = *(const float4*)&QL[g];
    }

    f32x4 oacc[4] = {};
    const int ar = (w * 16 + lr) * 136;
    const int js1 = min(8 * c + 8, i + 1);
    for (int js = 8 * c; js < js1; ++js) {
        const int s0 = js * 64;
        __syncthreads();
        #pragma unroll
        for (int it = 0; it < 2; ++it) {
            const int e = it * 256 + tid;
            const int s = e >> 3, c8 = e & 7;
            const long g = (long)(b * 2048 + s0 + s) * 64 + 8 * c8;
            *(float4*)&kt[s * 136 + 8 * c8]      = *(const float4*)&KH[g];
            *(float4*)&kt[s * 136 + 64 + 8 * c8] = *(const float4*)&KL[g];
        }
        #pragma unroll
        for (int it = 0; it < 2; ++it) {
            const int e = it * 256 + tid;
            const int h = e >> 3, c8 = e & 7;
            *(float4*)&vt[h * 72 + 8 * c8] =
                *(const float4*)&VT[(long)(b * 64 + h) * 2048 + s0 + 8 * c8];
        }
        if (tid < 64) rdt[tid] = 1.0f / D[b * 2048 + s0 + tid];
        __syncthreads();

        // dot phase (wave strip: t rows w*16..w*16+15)
        const bf16x8 ah0 = *(const bf16x8*)&qt[ar + quad * 8];
        const bf16x8 al0 = *(const bf16x8*)&qt[ar + 64 + quad * 8];
        const bf16x8 ah1 = *(const bf16x8*)&qt[ar + 32 + quad * 8];
        const bf16x8 al1 = *(const bf16x8*)&qt[ar + 96 + quad * 8];
        const bool diag = (js == i);
        #pragma unroll
        for (int nf = 0; nf < 4; ++nf) {
            const int br = (nf * 16 + lr) * 136;
            f32x4 cc = {};
            const bf16x8 bh0 = *(const bf16x8*)&kt[br + quad * 8];
            const bf16x8 bl0 = *(const bf16x8*)&kt[br + 64 + quad * 8];
            cc = MFMA(ah0, bh0, cc); cc = MFMA(ah0, bl0, cc); cc = MFMA(al0, bh0, cc);
            const bf16x8 bh1 = *(const bf16x8*)&kt[br + 32 + quad * 8];
            const bf16x8 bl1 = *(const bf16x8*)&kt[br + 96 + quad * 8];
            cc = MFMA(ah1, bh1, cc); cc = MFMA(ah1, bl1, cc); cc = MFMA(al1, bh1, cc);

            const int sl = nf * 16 + lr;
            const float rv = rdt[sl];
            #pragma unroll
            for (int r = 0; r < 4; ++r) {
                const int tl = w * 16 + quad * 4 + r;
                float wgt = __expf(cc[r]) * rv;
                if (diag && tl < sl) wgt = 0.f;
                wa[tl * 72 + sl] = f2bf(wgt);     // own-wave strip only
            }
        }
        // PV: A = wa strip (own rows), B = vt [h][s]
        #pragma unroll
        for (int kk = 0; kk < 2; ++kk) {
            const bf16x8 av = *(const bf16x8*)&wa[(w * 16 + lr) * 72 + kk * 32 + quad * 8];
            #pragma unroll
            for (int nf = 0; nf < 4; ++nf) {
                const bf16x8 bv = *(const bf16x8*)&vt[(nf * 16 + lr) * 72 + kk * 32 + quad * 8];
                oacc[nf] = MFMA(av, bv, oacc[nf]);
            }
        }
    }

    const bool single = (i < 8);
    #pragma unroll
    for (int nf = 0; nf < 4; ++nf) {
        const int h = nf * 16 + lr;
        #pragma unroll
        for (int r = 0; r < 4; ++r) {
            const int t = t0 + w * 16 + quad * 4 + r;
            const long o = (long)(b * 2048 + t) * 64 + h;
            if (single) out[o] = oacc[nf][r];
            else        atomicAdd(&out[o], oacc[nf][r]);
        }
    }
}

extern "C" void kernel_launch(void* const* d_in, const int* in_sizes, int n_in,
                              void* d_out, int out_size, void* d_ws, size_t ws_size,
                              hipStream_t stream)
{
    const float* idx = (const float*)d_in[0];
    const float* Wk  = (const float*)d_in[1];
    const float* Wq  = (const float*)d_in[2];
    const float* Wv  = (const float*)d_in[3];
    char* ws = (char*)d_ws;
    float* out = (float*)d_out;

    u16* FWH = (u16*)(ws + WH_OFF); u16* FWL = (u16*)(ws + WL_OFF);
    u16* QH = (u16*)(ws + QH_OFF); u16* QL = (u16*)(ws + QL_OFF);
    u16* KH = (u16*)(ws + KH_OFF); u16* KL = (u16*)(ws + KL_OFF);
    u16* VT = (u16*)(ws + VT_OFF);
    float* Dp = (float*)(ws + DD_OFF);

    hipMemsetAsync(out, 0, (size_t)8 * 2048 * 64 * sizeof(float), stream);
    hipMemsetAsync(Dp, 0, (size_t)8 * 2048 * sizeof(float), stream);

    wsplit_kernel<<<192, 128, 0, stream>>>(Wk, Wq, Wv, FWH, FWL);
    qkv_kernel<<<256, 512, 0, stream>>>(idx, FWH, FWL, QH, QL, KH, KL, VT);
    stats_kernel<<<dim3(80, 8), 256, 0, stream>>>(QH, QL, KH, KL, Dp);
    out_kernel<<<dim3(80, 8), 256, 0, stream>>>(QH, QL, KH, KL, VT, Dp, out);
}